// Round 7
// baseline (3691.207 us; speedup 1.0000x reference)
//
#include <hip/hip_runtime.h>

#define NN1 60000
#define EE1 600000
#define NN2 20000
#define EE2 150000
#define AA  60000

__device__ __forceinline__ float sigf(float x){ return 1.f/(1.f+expf(-x)); }
// wave-uniform broadcast of lane sl's value. sl may be a RUNTIME uniform
// (v_readlane_b32 takes an SGPR lane index), so loops need not unroll.
__device__ __forceinline__ float rlane(float v, int sl){
  return __int_as_float(__builtin_amdgcn_readlane(__float_as_int(v), sl));
}
// Broadcast 4 channels (ld.x..ld.w) of lane SL, then FMA into named scalars.
// ALL state is named scalars -> guaranteed VGPRs (rounds 1/3: arrays spill).
#define RL4(SL) hx = rlane(ld.x, SL); hy = rlane(ld.y, SL); hz = rlane(ld.z, SL); hw = rlane(ld.w, SL);
#define FMA4(A, W) A = fmaf(hx, W.x, A); A = fmaf(hy, W.y, A); A = fmaf(hz, W.z, A); A = fmaf(hw, W.w, A);
// transform tail: broadcast 4 channels of accumulator ACC (channel = lane) and
// FMA against weight float4 W = {W[4c4+q][lane]} into 'out'.
#define TRT(ACC, W) { \
  float s0 = rlane(ACC, (c4<<2)); float s1 = rlane(ACC, (c4<<2)|1); \
  float s2 = rlane(ACC, (c4<<2)|2); float s3 = rlane(ACC, (c4<<2)|3); \
  out = fmaf(s0, W.x, out); out = fmaf(s1, W.y, out); \
  out = fmaf(s2, W.z, out); out = fmaf(s3, W.w, out); }

// ---------- elementwise ----------
__global__ void k_relu(float* a, int n){
  int i = blockIdx.x*blockDim.x + threadIdx.x;
  if (i < n) a[i] = fmaxf(a[i], 0.f);
}
__global__ void k_copy(const float* __restrict__ a, float* __restrict__ o, int n){
  int i = blockIdx.x*blockDim.x + threadIdx.x;
  if (i < n) o[i] = a[i];
}

// ---------- edge type ----------
__global__ void k_etype(const float* __restrict__ ea, int* __restrict__ etype, int E){
  int e = blockIdx.x*blockDim.x + threadIdx.x;
  if (e >= E) return;
  const float* p = ea + (size_t)e*10;
  float best = p[0]; int bi = 0;
  #pragma unroll
  for (int k = 1; k < 4; ++k){ float v = p[k]; if (v > best){ best = v; bi = k; } }
  etype[e] = bi;
}

__global__ void k_coeff(const float* __restrict__ nt, const int* __restrict__ node_type,
                        float* __restrict__ coeff, int N){
  int n = blockIdx.x*blockDim.x + threadIdx.x;
  if (n < N) coeff[n] = nt[node_type[n]];
}

// ---------- batch row pointers (batch sorted ascending) ----------
__global__ void k_batchptr(const int* __restrict__ batch, int* __restrict__ rb, int N, int B){
  int n = blockIdx.x*blockDim.x + threadIdx.x;
  if (n >= N) return;
  int b = batch[n];
  if (n == 0){ for (int g = 0; g <= b; ++g) rb[g] = 0; }
  else {
    int pb = batch[n-1];
    for (int g = pb+1; g <= b; ++g) rb[g] = n;
  }
  if (n == N-1){ for (int g = b+1; g <= B; ++g) rb[g] = N; }
}

// ---------- weight prep ----------
// msg weights: conv_w[m][c][d] (m = (li*3+l)*4+t) -> w4[m][c4][d][q],
// float4 element (c4,d) = { W[4c4+0][d], W[4c4+1][d], W[4c4+2][d], W[4c4+3][d] }.
// In-kernel lane d reads float4 index c4*64+d: contiguous -> conflict-free b128.
__global__ void k_prep_msgw(const float* __restrict__ w, float* __restrict__ w4){
  int idx = blockIdx.x*256 + threadIdx.x;   // 60*4096 = 245760
  if (idx >= 245760) return;
  int m = idx >> 12, r = idx & 4095;
  int c4 = r >> 8, d = (r >> 2) & 63, q = r & 3;
  w4[idx] = w[m*4096 + (4*c4+q)*64 + d];
}
// GRU weights, three layouts:
//  wihT[l][t][c4][d][q] = wih[l][(64t+d)][4c4+q]  (tr3 fallback: lane d owns row 64t+d)
//  wihW[l][c4][j][q]    = wih[l][j][4c4+q]        (fused: lane l owns rows {l,64+l,128+l})
//  whh4[l][c4][j][q]    = whh[l][j][4c4+q]
__global__ void k_prep_gruw(const float* __restrict__ wih, const float* __restrict__ whh,
                            float* __restrict__ wihT, float* __restrict__ wihW,
                            float* __restrict__ whh4){
  int idx = blockIdx.x*256 + threadIdx.x;   // 5*12288 = 61440 each
  if (idx >= 61440) return;
  {
    int l = idx / 12288, r = idx % 12288;
    int t = r >> 12, rr = r & 4095;
    int c4 = rr >> 8, d = (rr >> 2) & 63, q = rr & 3;
    wihT[idx] = wih[l*12288 + (64*t + d)*64 + 4*c4 + q];
  }
  {
    int l = idx / 12288, rr = idx % 12288;
    int e = rr >> 2, q = rr & 3;
    int c4 = e / 192, j = e - c4*192;
    wihW[idx] = wih[l*12288 + j*64 + 4*c4 + q];
    whh4[idx] = whh[l*12288 + j*64 + 4*c4 + q];
  }
}

// ---------- set2set LSTM weight transpose to [k][j] (coalesced over gate row j) ----------
__global__ void k_s2strans(const float* __restrict__ wih0, const float* __restrict__ whh0,
                           const float* __restrict__ wih1, const float* __restrict__ whh1,
                           float* __restrict__ T){
  int idx = blockIdx.x*256 + threadIdx.x;
  if (idx < 32768){ int k = idx >> 8, j = idx & 255; T[idx] = wih0[j*128 + k]; }
  else if (idx < 49152){ int r = idx - 32768; int k = r >> 8, j = r & 255; T[idx] = whh0[j*64 + k]; }
  else if (idx < 65536){ int r = idx - 49152; int k = r >> 8, j = r & 255; T[idx] = wih1[j*64 + k]; }
  else if (idx < 81920){ int r = idx - 65536; int k = r >> 8, j = r & 255; T[idx] = whh1[j*64 + k]; }
}

// ---------- CSR build ----------
__global__ void k_hist(const int* __restrict__ dst, int* __restrict__ cnt, int E){
  int e = blockIdx.x*blockDim.x + threadIdx.x;
  if (e >= E) return;
  atomicAdd(&cnt[dst[e]], 1);
}
__global__ void k_chunksum(const int* __restrict__ cnt, int* __restrict__ csum, int M){
  __shared__ int sh[256];
  int base = blockIdx.x*1024;
  int s = 0;
  for (int i = threadIdx.x; i < 1024; i += 256){
    int idx = base + i;
    if (idx < M) s += cnt[idx];
  }
  sh[threadIdx.x] = s;
  __syncthreads();
  for (int o = 128; o; o >>= 1){
    if (threadIdx.x < o) sh[threadIdx.x] += sh[threadIdx.x + o];
    __syncthreads();
  }
  if (threadIdx.x == 0) csum[blockIdx.x] = sh[0];
}
__global__ void k_chunkscan(int* __restrict__ csum, int nchunk){
  __shared__ int sh[256];
  int i = threadIdx.x;
  int v = (i < nchunk) ? csum[i] : 0;
  sh[i] = v; __syncthreads();
  for (int o = 1; o < 256; o <<= 1){
    int y = (i >= o) ? sh[i-o] : 0;
    __syncthreads();
    sh[i] += y;
    __syncthreads();
  }
  if (i < nchunk) csum[i] = sh[i] - v;
  if (i == 255) csum[nchunk] = sh[255];
}
__global__ void k_chunkapply(const int* __restrict__ cnt, const int* __restrict__ csum,
                             int* __restrict__ R, int* __restrict__ cur, int M){
  __shared__ int sh[256];
  int base = blockIdx.x*1024;
  int i0 = base + threadIdx.x*4;
  int v[4]; int s = 0;
  #pragma unroll
  for (int k = 0; k < 4; ++k){ int idx = i0 + k; v[k] = (idx < M) ? cnt[idx] : 0; s += v[k]; }
  sh[threadIdx.x] = s; __syncthreads();
  for (int o = 1; o < 256; o <<= 1){
    int y = (threadIdx.x >= o) ? sh[threadIdx.x-o] : 0;
    __syncthreads();
    sh[threadIdx.x] += y;
    __syncthreads();
  }
  int run = csum[blockIdx.x] + sh[threadIdx.x] - s;
  #pragma unroll
  for (int k = 0; k < 4; ++k){
    int idx = i0 + k;
    if (idx < M){ R[idx] = run; cur[idx] = run; run += v[k]; }
  }
  if (threadIdx.x == 255 && base + 1024 >= M) R[M] = csum[blockIdx.x] + sh[255];
}
__global__ void k_scatter(const int* __restrict__ src, const int* __restrict__ dst,
                          const int* __restrict__ etype, int* __restrict__ cur,
                          int* __restrict__ ep, int E){
  int e = blockIdx.x*blockDim.x + threadIdx.x;
  if (e >= E) return;
  int t = etype ? etype[e] : 0;
  int pos = atomicAdd(&cur[dst[e]], 1);
  ep[pos] = (t << 20) | src[e];
}

// ---------- FUSED message pass: CSR gather of h + per-type transform ----------
// Algebra: aggr[d] = sum_e W_{t(e)} h[src] coeff[src] = sum_t W_t s_t[d],
//   s_t[d] = sum_{e of type t -> d} coeff[src] h[src].
// So gather h DIRECTLY (15MB, L2-resident; vs round-6 sweep gathering the 61MB
// tr slabs from L3) into 4 per-type register accumulators, then apply all 4
// matrices from LDS via readlane broadcast. Deletes the tr materialization
// (61MB write + 61MB gather) and 18 k_tr2 launches per fwd.
// t is wave-uniform per edge (readfirstlane -> scalar branch). No barriers
// after weight load; gather phase and FMA tail of different waves overlap.
__global__ __launch_bounds__(512) void k_sweep_tr4(
    const float* __restrict__ h, const int* __restrict__ R,
    const int* __restrict__ ep, const float* __restrict__ W4,
    const float* __restrict__ coeff, float* __restrict__ aggr, int N){
  extern __shared__ float4 wl[];           // [4][1024] = 64 KB
  for (int i = threadIdx.x; i < 4096; i += 512) wl[i] = ((const float4*)W4)[i];
  __syncthreads();
  int lane = threadIdx.x & 63, wv = threadIdx.x >> 6;   // 8 waves
  int nw = gridDim.x*8;
  for (int d = blockIdx.x*8 + wv; d < N; d += nw){
    int p = R[d], pend = R[d+1];
    float a0=0.f, a1=0.f, a2=0.f, a3=0.f;
    while (p < pend){
      int m = pend - p; if (m > 64) m = 64;
      int ev = (lane < m) ? ep[p + lane] : 0;
      for (int j = 0; j < m; ++j){
        int pk = __builtin_amdgcn_readfirstlane(__shfl(ev, j));
        int s = pk & 0xFFFFF, t = pk >> 20;
        float v = h[((size_t)s << 6) + lane] * coeff[s];
        if (t == 0) a0 += v;
        else if (t == 1) a1 += v;
        else if (t == 2) a2 += v;
        else a3 += v;
      }
      p += m;
    }
    float out = 0.f;
    for (int c4 = 0; c4 < 16; ++c4){
      int wb = (c4 << 6) + lane;
      float4 w0 = wl[wb], w1 = wl[1024+wb], w2 = wl[2048+wb], w3 = wl[3072+wb];
      TRT(a0, w0) TRT(a1, w1) TRT(a2, w2) TRT(a3, w3)
    }
    aggr[((size_t)d << 6) + lane] = out;
  }
}

// single-type variant for level-2 (no coeff, t=0 only), 16 KB static LDS
__global__ __launch_bounds__(512) void k_sweep_tr1(
    const float* __restrict__ h, const int* __restrict__ R,
    const int* __restrict__ ep, const float* __restrict__ W4,
    float* __restrict__ aggr, int N){
  __shared__ float4 wl[1024];
  for (int i = threadIdx.x; i < 1024; i += 512) wl[i] = ((const float4*)W4)[i];
  __syncthreads();
  int lane = threadIdx.x & 63, wv = threadIdx.x >> 6;
  int nw = gridDim.x*8;
  for (int d = blockIdx.x*8 + wv; d < N; d += nw){
    int p = R[d], pend = R[d+1];
    float a0 = 0.f;
    while (p < pend){
      int m = pend - p; if (m > 64) m = 64;
      int ev = (lane < m) ? ep[p + lane] : 0;
      for (int j = 0; j < m; ++j){
        int s = __builtin_amdgcn_readfirstlane(__shfl(ev, j)) & 0xFFFFF;
        a0 += h[((size_t)s << 6) + lane];
      }
      p += m;
    }
    float out = 0.f;
    for (int c4 = 0; c4 < 16; ++c4){
      float4 w0 = wl[(c4 << 6) + lane];
      TRT(a0, w0)
    }
    aggr[((size_t)d << 6) + lane] = out;
  }
}

// ---------- tr3: GRU-fallback gi transform (LDS weights + readlane) ----------
__global__ __launch_bounds__(256) void k_tr3(
    const float* __restrict__ h, const float* __restrict__ W4,
    float* __restrict__ tr, int N){
  __shared__ float4 wl[3072];                 // 48 KB (3 matrices)
  for (int i = threadIdx.x; i < 3072; i += 256) wl[i] = ((const float4*)W4)[i];
  __syncthreads();
  int lane = threadIdx.x & 63, w = threadIdx.x >> 6;
  int ng = N >> 2, stride = gridDim.x*4;
  for (int g = blockIdx.x*4 + w; g < ng; g += stride){
    int n0 = g << 2;
    float4 ld = ((const float4*)(h + ((size_t)n0 << 6)))[lane];
    float a00=0.f,a01=0.f,a02=0.f,a03=0.f;
    float a10=0.f,a11=0.f,a12=0.f,a13=0.f;
    float a20=0.f,a21=0.f,a22=0.f,a23=0.f;
    for (int c4 = 0; c4 < 16; ++c4){
      float4 w0 = wl[(c4 << 6) + lane];
      float4 w1 = wl[1024 + (c4 << 6) + lane];
      float4 w2 = wl[2048 + (c4 << 6) + lane];
      float hx, hy, hz, hw;
      RL4(c4)       FMA4(a00, w0) FMA4(a10, w1) FMA4(a20, w2)
      RL4(16|c4)    FMA4(a01, w0) FMA4(a11, w1) FMA4(a21, w2)
      RL4(32|c4)    FMA4(a02, w0) FMA4(a12, w1) FMA4(a22, w2)
      RL4(48|c4)    FMA4(a03, w0) FMA4(a13, w1) FMA4(a23, w2)
    }
    float* o0 = tr + ((size_t)n0 << 6) + lane;
    o0[0] = a00; o0[64] = a01; o0[128] = a02; o0[192] = a03;
    float* o1 = tr + (((size_t)N + n0) << 6) + lane;
    o1[0] = a10; o1[64] = a11; o1[128] = a12; o1[192] = a13;
    float* o2 = tr + (((size_t)2*N + n0) << 6) + lane;
    o2[0] = a20; o2[64] = a21; o2[128] = a22; o2[192] = a23;
  }
}

// ---------- fully fused GRU: both GEMVs + pointwise in ONE kernel ----------
// wih AND whh in LDS (96KB, 1 block/CU, 16 waves = 4/SIMD). GRU algebra folds
// gi_r+gh_r and gi_z+gh_z into single accumulators. Per 4-node group: 2
// coalesced dwordx4 loads, 96 conflict-free ds_read_b128, 512 rl + 1536 fma,
// in-lane pointwise, ZERO barriers in the loop.  [round 6: -950us]
#define RLAH(SL) \
  ax = rlane(la.x, SL); ay = rlane(la.y, SL); az2 = rlane(la.z, SL); aw = rlane(la.w, SL); \
  hx = rlane(ld.x, SL); hy = rlane(ld.y, SL); hz  = rlane(ld.z, SL); hw = rlane(ld.w, SL);
#define GACC(SL, R, Z, P, Q) RLAH(SL) \
  R = fmaf(ax,iwr.x,R); R = fmaf(ay,iwr.y,R); R = fmaf(az2,iwr.z,R); R = fmaf(aw,iwr.w,R); \
  R = fmaf(hx,hwr.x,R); R = fmaf(hy,hwr.y,R); R = fmaf(hz,hwr.z,R);  R = fmaf(hw,hwr.w,R); \
  Z = fmaf(ax,iwz.x,Z); Z = fmaf(ay,iwz.y,Z); Z = fmaf(az2,iwz.z,Z); Z = fmaf(aw,iwz.w,Z); \
  Z = fmaf(hx,hwz.x,Z); Z = fmaf(hy,hwz.y,Z); Z = fmaf(hz,hwz.z,Z);  Z = fmaf(hw,hwz.w,Z); \
  P = fmaf(ax,iwn.x,P); P = fmaf(ay,iwn.y,P); P = fmaf(az2,iwn.z,P); P = fmaf(aw,iwn.w,P); \
  Q = fmaf(hx,hwn.x,Q); Q = fmaf(hy,hwn.y,Q); Q = fmaf(hz,hwn.z,Q);  Q = fmaf(hw,hwn.w,Q);
#define GFIN(K, R, Z, P, Q) { \
    size_t off = base + ((size_t)(K) << 6) + lane; \
    float hv = h[off]; \
    float r = sigf(R), z = sigf(Z); \
    float nn = tanhf(P + r*Q); \
    h[off] = (1.f - z)*nn + z*hv; }
__global__ __launch_bounds__(1024, 4) void k_gru_fused(
    const float* __restrict__ aggr, float* __restrict__ h,
    const float* __restrict__ wihW, const float* __restrict__ whhW,
    const float* __restrict__ bih, const float* __restrict__ bhh, int N){
  extern __shared__ float4 wl[];           // [6144]: wih | whh, 96 KB
  for (int i = threadIdx.x; i < 6144; i += 1024)
    wl[i] = (i < 3072) ? ((const float4*)wihW)[i] : ((const float4*)whhW)[i - 3072];
  __syncthreads();
  const float4* wi = wl;
  const float4* wh = wl + 3072;
  int lane = threadIdx.x & 63, wv = threadIdx.x >> 6;
  float br  = bih[lane]     + bhh[lane];
  float bz  = bih[64+lane]  + bhh[64+lane];
  float bp  = bih[128+lane];                // gi_n bias
  float bq  = bhh[128+lane];                // gh_n bias
  int ng = N >> 2, stride = gridDim.x*16;
  for (int g = blockIdx.x*16 + wv; g < ng; g += stride){
    int n0 = g << 2;
    size_t base = (size_t)n0 << 6;
    float4 la = ((const float4*)(aggr + base))[lane];
    float4 ld = ((const float4*)(h + base))[lane];
    float r0=br, r1=br, r2=br, r3=br;
    float z0=bz, z1=bz, z2=bz, z3=bz;
    float p0=bp, p1=bp, p2=bp, p3=bp;
    float q0=bq, q1=bq, q2=bq, q3=bq;
    for (int c4 = 0; c4 < 16; ++c4){
      int wb = c4*192 + lane;
      float4 iwr = wi[wb], iwz = wi[wb+64], iwn = wi[wb+128];
      float4 hwr = wh[wb], hwz = wh[wb+64], hwn = wh[wb+128];
      float ax, ay, az2, aw, hx, hy, hz, hw;
      GACC(c4,    r0, z0, p0, q0)
      GACC(16|c4, r1, z1, p1, q1)
      GACC(32|c4, r2, z2, p2, q2)
      GACC(48|c4, r3, z3, p3, q3)
    }
    GFIN(0, r0, z0, p0, q0)
    GFIN(1, r1, z1, p1, q1)
    GFIN(2, r2, z2, p2, q2)
    GFIN(3, r3, z3, p3, q3)
  }
}

// ---------- GRU finalize fallback (used only if 96KB dynamic LDS refused) ----------
#define GRUACC(SL, RK, ZK, NK) RL4(SL) FMA4(RK, wr) FMA4(ZK, wz) FMA4(NK, wn)
#define GRUFIN(K, RK, ZK, NK) { \
    size_t off = base + (K << 6) + lane; \
    float gir = gi[off], giz = gi[S + off], gin = gi[2*S + off]; \
    float hv = h[off]; \
    float r = sigf(gir + bir + RK); \
    float z = sigf(giz + biz + ZK); \
    float nv = tanhf(gin + bin_ + r*NK); \
    h[off] = (1.f - z)*nv + z*hv; }
__global__ __launch_bounds__(256, 3) void k_gru_finW(
    const float* __restrict__ gi, float* __restrict__ h,
    const float* __restrict__ whh4,
    const float* __restrict__ bih, const float* __restrict__ bhh, int N){
  __shared__ float4 wh[3072];              // [c4][192] = whh[j][4c4+q], 48KB
  for (int i = threadIdx.x; i < 3072; i += 256) wh[i] = ((const float4*)whh4)[i];
  __syncthreads();
  int lane = threadIdx.x & 63, w = threadIdx.x >> 6;
  float bir = bih[lane], biz = bih[64+lane], bin_ = bih[128+lane];
  float bhr = bhh[lane], bhz = bhh[64+lane], bhn = bhh[128+lane];
  size_t S = (size_t)N << 6;
  int ng = N >> 2, stride = gridDim.x*4;
  for (int g = blockIdx.x*4 + w; g < ng; g += stride){
    int n0 = g << 2;
    size_t base = (size_t)n0 << 6;
    float4 ld = ((const float4*)(h + base))[lane];
    float ar0=bhr, ar1=bhr, ar2=bhr, ar3=bhr;
    float az0=bhz, az1=bhz, az2=bhz, az3=bhz;
    float an0=bhn, an1=bhn, an2=bhn, an3=bhn;
    for (int c4 = 0; c4 < 16; ++c4){
      int wb = c4*192 + lane;
      float4 wr = wh[wb];
      float4 wz = wh[wb + 64];
      float4 wn = wh[wb + 128];
      float hx, hy, hz, hw;
      GRUACC(c4,    ar0, az0, an0)
      GRUACC(16|c4, ar1, az1, an1)
      GRUACC(32|c4, ar2, az2, an2)
      GRUACC(48|c4, ar3, az3, an3)
    }
    GRUFIN(0, ar0, az0, an0)
    GRUFIN(1, ar1, az1, an1)
    GRUFIN(2, ar2, az2, an2)
    GRUFIN(3, ar3, az3, an3)
  }
}

// ---------- batch norm over nodes ----------
__global__ void k_bnstats(const float* __restrict__ h, float* __restrict__ stats, int N){
  int c = threadIdx.x & 63;
  int g = threadIdx.x >> 6;
  float s = 0.f, s2 = 0.f;
  for (int n = blockIdx.x*4 + g; n < N; n += gridDim.x*4){
    float v = h[(size_t)n*64 + c]; s += v; s2 += v*v;
  }
  __shared__ float sh[4][64], sh2[4][64];
  sh[g][c] = s; sh2[g][c] = s2;
  __syncthreads();
  if (g == 0){
    float ts = sh[0][c]+sh[1][c]+sh[2][c]+sh[3][c];
    float t2 = sh2[0][c]+sh2[1][c]+sh2[2][c]+sh2[3][c];
    atomicAdd(&stats[c], ts); atomicAdd(&stats[64+c], t2);
  }
}
__global__ void k_bnapply(float* __restrict__ h, const float* __restrict__ stats,
                          const float* __restrict__ g, const float* __restrict__ b,
                          int N, int relu){
  int i = blockIdx.x*blockDim.x + threadIdx.x;
  if (i >= N*64) return;
  int c = i & 63;
  float inv = 1.f/(float)N;
  float mean = stats[c]*inv;
  float var  = stats[64+c]*inv - mean*mean;
  float y = (h[i]-mean)*rsqrtf(var + 1e-5f)*g[c] + b[c];
  if (relu) y = fmaxf(y, 0.f);
  h[i] = y;
}

// ---------- avg_pool ----------
__global__ void k_pool_acc(const float* __restrict__ h, const int* __restrict__ asrc,
                           const int* __restrict__ adst, float* __restrict__ h2,
                           float* __restrict__ cnt, int A){
  int i = blockIdx.x*blockDim.x + threadIdx.x;
  if (i >= A*64) return;
  int a = i >> 6, c = i & 63;
  int s = asrc[a], d = adst[a];
  atomicAdd(&h2[(size_t)d*64 + c], h[(size_t)s*64 + c]);
  if (c == 0) atomicAdd(&cnt[d], 1.f);
}
__global__ void k_pool_div(float* __restrict__ h2, const float* __restrict__ cnt, int N){
  int i = blockIdx.x*blockDim.x + threadIdx.x;
  if (i >= N*64) return;
  h2[i] = h2[i] / fmaxf(cnt[i >> 6], 1.f);
}

// ---------- fully fused set2set: one block (1024 thr = 16 waves) per graph ----------
__global__ __launch_bounds__(1024) void k_set2set(const float* __restrict__ x, const int* __restrict__ rb,
                          const float* __restrict__ T,
                          const float* __restrict__ b0, const float* __restrict__ b1,
                          float* __restrict__ xout){
  int b = blockIdx.x, j = threadIdx.x;
  int w = j >> 6, lane = j & 63;
  __shared__ float qstar[128], h0[64], c0[64], h1[64], c1[64];
  __shared__ float gs[256], wmax[16], wsum[16], racc[16][64];
  if (j < 128) qstar[j] = 0.f;
  if (j < 64){ h0[j] = 0.f; c0[j] = 0.f; h1[j] = 0.f; c1[j] = 0.f; }
  __syncthreads();
  int n0 = rb[b], n1 = rb[b+1];
  const float* T0 = T;            // wih0T [128][256]
  const float* T1 = T + 32768;    // whh0T [64][256]
  const float* T2 = T + 49152;    // wih1T [64][256]
  const float* T3 = T + 65536;    // whh1T [64][256]
  for (int s = 0; s < 5; ++s){
    if (j < 256){
      float a0 = b0[j], a1 = 0.f, a2 = 0.f, a3 = 0.f;
      #pragma unroll 4
      for (int k = 0; k < 128; k += 4){
        a0 = fmaf(T0[(k+0)*256 + j], qstar[k+0], a0);
        a1 = fmaf(T0[(k+1)*256 + j], qstar[k+1], a1);
        a2 = fmaf(T0[(k+2)*256 + j], qstar[k+2], a2);
        a3 = fmaf(T0[(k+3)*256 + j], qstar[k+3], a3);
      }
      #pragma unroll 4
      for (int k = 0; k < 64; k += 4){
        a0 = fmaf(T1[(k+0)*256 + j], h0[k+0], a0);
        a1 = fmaf(T1[(k+1)*256 + j], h0[k+1], a1);
        a2 = fmaf(T1[(k+2)*256 + j], h0[k+2], a2);
        a3 = fmaf(T1[(k+3)*256 + j], h0[k+3], a3);
      }
      gs[j] = (a0 + a1) + (a2 + a3);
    }
    __syncthreads();
    if (j < 64){
      float ig = sigf(gs[j]);
      float fg = sigf(gs[64+j]);
      float gg = tanhf(gs[128+j]);
      float og = sigf(gs[192+j]);
      float cn = fg*c0[j] + ig*gg;
      c0[j] = cn;
      h0[j] = og*tanhf(cn);
    }
    __syncthreads();
    if (j < 256){
      float a0 = b1[j], a1 = 0.f, a2 = 0.f, a3 = 0.f;
      #pragma unroll 4
      for (int k = 0; k < 64; k += 4){
        a0 = fmaf(T2[(k+0)*256 + j], h0[k+0], a0);
        a1 = fmaf(T2[(k+1)*256 + j], h0[k+1], a1);
        a2 = fmaf(T2[(k+2)*256 + j], h0[k+2], a2);
        a3 = fmaf(T2[(k+3)*256 + j], h0[k+3], a3);
      }
      #pragma unroll 4
      for (int k = 0; k < 64; k += 4){
        a0 = fmaf(T3[(k+0)*256 + j], h1[k+0], a0);
        a1 = fmaf(T3[(k+1)*256 + j], h1[k+1], a1);
        a2 = fmaf(T3[(k+2)*256 + j], h1[k+2], a2);
        a3 = fmaf(T3[(k+3)*256 + j], h1[k+3], a3);
      }
      gs[j] = (a0 + a1) + (a2 + a3);
    }
    __syncthreads();
    if (j < 64){
      float ig = sigf(gs[j]);
      float fg = sigf(gs[64+j]);
      float gg = tanhf(gs[128+j]);
      float og = sigf(gs[192+j]);
      float cn = fg*c1[j] + ig*gg;
      c1[j] = cn;
      float hn = og*tanhf(cn);
      h1[j] = hn;
      qstar[j] = hn;
    }
    __syncthreads();
    float lmax = -3.4e38f;
    for (int n = n0 + w; n < n1; n += 16){
      float v = x[(size_t)n*64 + lane]*qstar[lane];
      #pragma unroll
      for (int o = 32; o; o >>= 1) v += __shfl_xor(v, o);
      lmax = fmaxf(lmax, v);
    }
    if (lane == 0) wmax[w] = lmax;
    __syncthreads();
    float bmax = wmax[0];
    #pragma unroll
    for (int k = 1; k < 16; ++k) bmax = fmaxf(bmax, wmax[k]);
    float lsum = 0.f, lr = 0.f;
    for (int n = n0 + w; n < n1; n += 16){
      float xv = x[(size_t)n*64 + lane];
      float v = xv*qstar[lane];
      #pragma unroll
      for (int o = 32; o; o >>= 1) v += __shfl_xor(v, o);
      float wexp = expf(v - bmax);
      lsum += wexp;
      lr = fmaf(wexp, xv, lr);
    }
    if (lane == 0) wsum[w] = lsum;
    racc[w][lane] = lr;
    __syncthreads();
    if (j < 64){
      float r = 0.f, denom = 0.f;
      #pragma unroll
      for (int k = 0; k < 16; ++k){ r += racc[k][j]; denom += wsum[k]; }
      qstar[64 + j] = (denom > 0.f) ? (r/denom) : 0.f;
    }
    __syncthreads();
  }
  if (j < 128) xout[(size_t)b*128 + j] = qstar[j];
}

// ---------- head ----------
__global__ void k_concat(const float* __restrict__ x1, const float* __restrict__ x2,
                         float* __restrict__ z){
  int i = blockIdx.x*blockDim.x + threadIdx.x;
  if (i >= 256*256) return;
  int b = i >> 8, c = i & 255;
  z[i] = (c < 128) ? x1[b*128 + c] : x2[b*128 + (c - 128)];
}
__global__ void k_bn_par(float* __restrict__ X, const float* __restrict__ g,
                         const float* __restrict__ b, int F, int relu){
  int f = blockIdx.x, i = threadIdx.x;
  float v = X[(size_t)i*F + f];
  __shared__ float s1[256], s2[256];
  s1[i] = v; s2[i] = v*v;
  __syncthreads();
  for (int o = 128; o; o >>= 1){
    if (i < o){ s1[i] += s1[i+o]; s2[i] += s2[i+o]; }
    __syncthreads();
  }
  float mean = s1[0]*(1.f/256.f);
  float var  = s2[0]*(1.f/256.f) - mean*mean;
  float y = (v - mean)*rsqrtf(var + 1e-5f)*g[f] + b[f];
  if (relu) y = fmaxf(y, 0.f);
  X[(size_t)i*F + f] = y;
}
__global__ void k_fc(const float* __restrict__ X, const float* __restrict__ W,
                     const float* __restrict__ bias, float* __restrict__ Y, int K, int F){
  int b = blockIdx.x, f = threadIdx.x;
  if (f >= F) return;
  const float* xr = X + (size_t)b*K;
  const float* wr = W + (size_t)f*K;
  float acc = bias[f];
  for (int k = 0; k < K; ++k) acc = fmaf(xr[k], wr[k], acc);
  Y[(size_t)b*F + f] = acc;
}
__global__ void k_fc_out(const float* __restrict__ z2, const float* __restrict__ w,
                         const float* __restrict__ bias, float* __restrict__ out){
  int b = blockIdx.x*blockDim.x + threadIdx.x;
  if (b >= 256) return;
  float acc = bias[0];
  #pragma unroll
  for (int k = 0; k < 64; ++k) acc = fmaf(z2[b*64 + k], w[k], acc);
  out[b] = acc;
}

extern "C" void kernel_launch(void* const* d_in, const int* in_sizes, int n_in,
                              void* d_out, int out_size, void* d_ws, size_t ws_size,
                              hipStream_t stream) {
  const float* x_in     = (const float*)d_in[0];
  const float* edge_attr= (const float*)d_in[1];
  const float* conv_w   = (const float*)d_in[2];
  const float* conv_wih = (const float*)d_in[3];
  const float* conv_whh = (const float*)d_in[4];
  const float* conv_bih = (const float*)d_in[5];
  const float* conv_bhh = (const float*)d_in[6];
  const float* conv_nt  = (const float*)d_in[7];
  const float* s1_wih0 = (const float*)d_in[8];
  const float* s1_whh0 = (const float*)d_in[9];
  const float* s1_b0   = (const float*)d_in[10];
  const float* s1_wih1 = (const float*)d_in[11];
  const float* s1_whh1 = (const float*)d_in[12];
  const float* s1_b1   = (const float*)d_in[13];
  const float* s2_wih0 = (const float*)d_in[14];
  const float* s2_whh0 = (const float*)d_in[15];
  const float* s2_b0   = (const float*)d_in[16];
  const float* s2_wih1 = (const float*)d_in[17];
  const float* s2_whh1 = (const float*)d_in[18];
  const float* s2_b1   = (const float*)d_in[19];
  const float* bn_g    = (const float*)d_in[20];
  const float* bn_b    = (const float*)d_in[21];
  const float* prebn_g = (const float*)d_in[22];
  const float* prebn_b = (const float*)d_in[23];
  const float* fc_w0   = (const float*)d_in[24];
  const float* fc_b0   = (const float*)d_in[25];
  const float* fc_w1   = (const float*)d_in[26];
  const float* fc_b1   = (const float*)d_in[27];
  const float* fc_w2   = (const float*)d_in[28];
  const float* fc_b2   = (const float*)d_in[29];
  const float* fcbn_g0 = (const float*)d_in[30];
  const float* fcbn_b0 = (const float*)d_in[31];
  const float* fcbn_g1 = (const float*)d_in[32];
  const float* fcbn_b1 = (const float*)d_in[33];
  const int* edge_index   = (const int*)d_in[34];
  const int* node_type    = (const int*)d_in[35];
  const int* batch        = (const int*)d_in[36];
  const int* assign_src   = (const int*)d_in[37];
  const int* assign_dst   = (const int*)d_in[38];
  const int* edge_index_2 = (const int*)d_in[39];
  const int* batch_2      = (const int*)d_in[40];
  (void)in_sizes; (void)n_in; (void)out_size; (void)ws_size;

  // dynamic-LDS opt-ins (host-side, graph-capture-safe). 96KB path proven in r6.
  int fused_ok = (hipFuncSetAttribute((const void*)k_gru_fused,
                    hipFuncAttributeMaxDynamicSharedMemorySize, 98304) == hipSuccess);
  hipFuncSetAttribute((const void*)k_sweep_tr4,
                    hipFuncAttributeMaxDynamicSharedMemorySize, 65536);

  // ---- workspace layout ----
  float* Wp = (float*)d_ws;
  size_t o = 0;
  auto alloc = [&](size_t n){ float* p = Wp + o; o += n; return p; };
  float* h     = alloc((size_t)NN1*64);
  float* tr    = alloc((size_t)4*NN1*64);   // gi slabs for GRU fallback only
  float* aggr  = alloc((size_t)NN1*64);
  float* coeff = alloc(NN1);
  float* h2    = alloc((size_t)NN2*64);
  float* cnt   = alloc(NN2);
  float* x1    = alloc(256*128);
  float* x2    = alloc(256*128);
  float* z     = alloc(256*256);
  float* z1    = alloc(256*128);
  float* z2    = alloc(256*64);
  float* stats = alloc(128);
  float* w4    = alloc(245760);
  float* wihT  = alloc(61440);
  float* wihW  = alloc(61440);
  float* whh4  = alloc(61440);
  float* s2sT1 = alloc(81920);
  float* s2sT2 = alloc(81920);
  int* etype = (int*)alloc(EE1);
  int* cnt1  = (int*)alloc(NN1);
  int* R1    = (int*)alloc(NN1 + 1);
  int* ep1   = (int*)alloc(EE1);
  int* cnt2  = (int*)alloc(NN2);
  int* R2    = (int*)alloc(NN2 + 1);
  int* ep2   = (int*)alloc(EE2);
  int* csum  = (int*)alloc(260);
  int* rb1   = (int*)alloc(257);
  int* rb2   = (int*)alloc(257);

  const int* src1 = edge_index;
  const int* dst1 = edge_index + EE1;
  const int* src2 = edge_index_2;
  const int* dst2 = edge_index_2 + EE2;

  k_etype<<<(EE1+255)/256, 256, 0, stream>>>(edge_attr, etype, EE1);
  k_copy<<<(NN1*64+255)/256, 256, 0, stream>>>(x_in, h, NN1*64);
  k_prep_msgw<<<(245760+255)/256, 256, 0, stream>>>(conv_w, w4);
  k_prep_gruw<<<(61440+255)/256, 256, 0, stream>>>(conv_wih, conv_whh, wihT, wihW, whh4);
  k_s2strans<<<(81920+255)/256, 256, 0, stream>>>(s1_wih0, s1_whh0, s1_wih1, s1_whh1, s2sT1);
  k_s2strans<<<(81920+255)/256, 256, 0, stream>>>(s2_wih0, s2_whh0, s2_wih1, s2_whh1, s2sT2);
  k_batchptr<<<(NN1+255)/256, 256, 0, stream>>>(batch, rb1, NN1, 256);
  k_batchptr<<<(NN2+255)/256, 256, 0, stream>>>(batch_2, rb2, NN2, 256);

  {  // level-1 CSR (keys = dst; etype packed into edge payload)
    int M = NN1, nchunk = (M + 1023)/1024;
    hipMemsetAsync(cnt1, 0, (size_t)M*sizeof(int), stream);
    k_hist<<<(EE1+255)/256, 256, 0, stream>>>(dst1, cnt1, EE1);
    k_chunksum<<<nchunk, 256, 0, stream>>>(cnt1, csum, M);
    k_chunkscan<<<1, 256, 0, stream>>>(csum, nchunk);
    k_chunkapply<<<nchunk, 256, 0, stream>>>(cnt1, csum, R1, cnt1, M);
    k_scatter<<<(EE1+255)/256, 256, 0, stream>>>(src1, dst1, etype, cnt1, ep1, EE1);
  }
  {  // level-2 CSR
    int M = NN2, nchunk = (M + 1023)/1024;
    hipMemsetAsync(cnt2, 0, (size_t)M*sizeof(int), stream);
    k_hist<<<(EE2+255)/256, 256, 0, stream>>>(dst2, cnt2, EE2);
    k_chunksum<<<nchunk, 256, 0, stream>>>(cnt2, csum, M);
    k_chunkscan<<<1, 256, 0, stream>>>(csum, nchunk);
    k_chunkapply<<<nchunk, 256, 0, stream>>>(cnt2, csum, R2, cnt2, M);
    k_scatter<<<(EE2+255)/256, 256, 0, stream>>>(src2, dst2, nullptr, cnt2, ep2, EE2);
  }

  // GRU: fused (gi+gh+pointwise, 96KB LDS) or fallback (tr3 + finW)
  auto gru = [&](float* hbuf, int N, int lidx){
    if (fused_ok){
      k_gru_fused<<<256, 1024, 98304, stream>>>(aggr, hbuf,
          wihW + (size_t)lidx*12288, whh4 + (size_t)lidx*12288,
          conv_bih + lidx*192, conv_bhh + lidx*192, N);
    } else {
      k_tr3<<<768, 256, 0, stream>>>(aggr, wihT + (size_t)lidx*12288, tr, N);
      k_gru_finW<<<768, 256, 0, stream>>>(tr, hbuf, whh4 + (size_t)lidx*12288,
          conv_bih + lidx*192, conv_bhh + lidx*192, N);
    }
  };

  // ---- level-1: 3x MGGC(L=3) + BN + ReLU ----
  for (int i = 0; i < 3; ++i){
    k_coeff<<<(NN1+255)/256, 256, 0, stream>>>(conv_nt + i*9, node_type, coeff, NN1);
    for (int l = 0; l < 3; ++l){
      const float* W4l = w4 + (size_t)(i*3+l)*16384;   // 4 matrices, float4 layout
      k_sweep_tr4<<<512, 512, 65536, stream>>>(h, R1, ep1, W4l, coeff, aggr, NN1);
      gru(h, NN1, i);
    }
    hipMemsetAsync(stats, 0, 128*sizeof(float), stream);
    k_bnstats<<<256, 256, 0, stream>>>(h, stats, NN1);
    k_bnapply<<<(NN1*64+255)/256, 256, 0, stream>>>(h, stats, bn_g + i*64, bn_b + i*64, NN1, 1);
  }

  // ---- set2set (single fused kernel, 1024 threads/graph) ----
  k_set2set<<<256, 1024, 0, stream>>>(h, rb1, s2sT1, s1_b0, s1_b1, x1);

  // ---- avg_pool ----
  hipMemsetAsync(h2, 0, (size_t)NN2*64*sizeof(float), stream);
  hipMemsetAsync(cnt, 0, (size_t)NN2*sizeof(float), stream);
  k_pool_acc<<<(AA*64+255)/256, 256, 0, stream>>>(h, assign_src, assign_dst, h2, cnt, AA);
  k_pool_div<<<(NN2*64+255)/256, 256, 0, stream>>>(h2, cnt, NN2);

  // ---- level-2: 2x relu(MGGC(L=3)), only edge type 0 ----
  for (int L = 3; L < 5; ++L){
    for (int l = 0; l < 3; ++l){
      const float* W4l = w4 + (size_t)(L*3+l)*16384;   // t=0 slice used
      k_sweep_tr1<<<512, 512, 0, stream>>>(h2, R2, ep2, W4l, aggr, NN2);
      gru(h2, NN2, L);
    }
    k_relu<<<(NN2*64+255)/256, 256, 0, stream>>>(h2, NN2*64);
  }

  k_set2set<<<256, 1024, 0, stream>>>(h2, rb2, s2sT2, s2_b0, s2_b1, x2);

  // ---- head ----
  k_concat<<<256, 256, 0, stream>>>(x1, x2, z);
  k_bn_par<<<256, 256, 0, stream>>>(z, prebn_g, prebn_b, 256, 0);
  k_fc<<<256, 128, 0, stream>>>(z, fc_w0, fc_b0, z1, 256, 128);
  k_bn_par<<<128, 256, 0, stream>>>(z1, fcbn_g0, fcbn_b0, 128, 1);
  k_fc<<<256, 64, 0, stream>>>(z1, fc_w1, fc_b1, z2, 128, 64);
  k_bn_par<<<64, 256, 0, stream>>>(z2, fcbn_g1, fcbn_b1, 64, 1);
  k_fc_out<<<4, 64, 0, stream>>>(z2, fc_w2, fc_b2, (float*)d_out);
}

// Round 8
// 2397.505 us; speedup vs baseline: 1.5396x; 1.5396x over previous
//
#include <hip/hip_runtime.h>

#define NN1 60000
#define EE1 600000
#define NN2 20000
#define EE2 150000
#define AA  60000

__device__ __forceinline__ float sigf(float x){ return 1.f/(1.f+expf(-x)); }
// wave-uniform broadcast of lane sl's value. sl may be a RUNTIME uniform
// (v_readlane_b32 takes an SGPR lane index), so loops need not unroll.
__device__ __forceinline__ float rlane(float v, int sl){
  return __int_as_float(__builtin_amdgcn_readlane(__float_as_int(v), sl));
}
// Broadcast 4 channels (ld.x..ld.w) of lane SL, then FMA into named scalars.
// ALL state is named scalars -> guaranteed VGPRs (rounds 1/3: arrays spill).
#define RL4(SL) hx = rlane(ld.x, SL); hy = rlane(ld.y, SL); hz = rlane(ld.z, SL); hw = rlane(ld.w, SL);
#define FMA4(A, W) A = fmaf(hx, W.x, A); A = fmaf(hy, W.y, A); A = fmaf(hz, W.z, A); A = fmaf(hw, W.w, A);

// ---------- elementwise ----------
__global__ void k_relu(float* a, int n){
  int i = blockIdx.x*blockDim.x + threadIdx.x;
  if (i < n) a[i] = fmaxf(a[i], 0.f);
}
__global__ void k_copy(const float* __restrict__ a, float* __restrict__ o, int n){
  int i = blockIdx.x*blockDim.x + threadIdx.x;
  if (i < n) o[i] = a[i];
}

// ---------- edge type ----------
__global__ void k_etype(const float* __restrict__ ea, int* __restrict__ etype, int E){
  int e = blockIdx.x*blockDim.x + threadIdx.x;
  if (e >= E) return;
  const float* p = ea + (size_t)e*10;
  float best = p[0]; int bi = 0;
  #pragma unroll
  for (int k = 1; k < 4; ++k){ float v = p[k]; if (v > best){ best = v; bi = k; } }
  etype[e] = bi;
}

__global__ void k_coeff(const float* __restrict__ nt, const int* __restrict__ node_type,
                        float* __restrict__ coeff, int N){
  int n = blockIdx.x*blockDim.x + threadIdx.x;
  if (n < N) coeff[n] = nt[node_type[n]];
}

// ---------- batch row pointers (batch sorted ascending) ----------
__global__ void k_batchptr(const int* __restrict__ batch, int* __restrict__ rb, int N, int B){
  int n = blockIdx.x*blockDim.x + threadIdx.x;
  if (n >= N) return;
  int b = batch[n];
  if (n == 0){ for (int g = 0; g <= b; ++g) rb[g] = 0; }
  else {
    int pb = batch[n-1];
    for (int g = pb+1; g <= b; ++g) rb[g] = n;
  }
  if (n == N-1){ for (int g = b+1; g <= B; ++g) rb[g] = N; }
}

// ---------- weight prep ----------
// msg weights: conv_w[m][c][d] (m = (li*3+l)*4+t) -> w4[m][c4][d][q],
// float4 element (c4,d) = { W[4c4+0][d], W[4c4+1][d], W[4c4+2][d], W[4c4+3][d] }.
// In-kernel lane d reads float4 index c4*64+d: contiguous -> conflict-free b128.
__global__ void k_prep_msgw(const float* __restrict__ w, float* __restrict__ w4){
  int idx = blockIdx.x*256 + threadIdx.x;   // 60*4096 = 245760
  if (idx >= 245760) return;
  int m = idx >> 12, r = idx & 4095;
  int c4 = r >> 8, d = (r >> 2) & 63, q = r & 3;
  w4[idx] = w[m*4096 + (4*c4+q)*64 + d];
}
// GRU weights, three layouts:
//  wihT[l][t][c4][d][q] = wih[l][(64t+d)][4c4+q]  (tr3 fallback: lane d owns row 64t+d)
//  wihW[l][c4][j][q]    = wih[l][j][4c4+q]        (fused: lane l owns rows {l,64+l,128+l})
//  whh4[l][c4][j][q]    = whh[l][j][4c4+q]
__global__ void k_prep_gruw(const float* __restrict__ wih, const float* __restrict__ whh,
                            float* __restrict__ wihT, float* __restrict__ wihW,
                            float* __restrict__ whh4){
  int idx = blockIdx.x*256 + threadIdx.x;   // 5*12288 = 61440 each
  if (idx >= 61440) return;
  {
    int l = idx / 12288, r = idx % 12288;
    int t = r >> 12, rr = r & 4095;
    int c4 = rr >> 8, d = (rr >> 2) & 63, q = rr & 3;
    wihT[idx] = wih[l*12288 + (64*t + d)*64 + 4*c4 + q];
  }
  {
    int l = idx / 12288, rr = idx % 12288;
    int e = rr >> 2, q = rr & 3;
    int c4 = e / 192, j = e - c4*192;
    wihW[idx] = wih[l*12288 + j*64 + 4*c4 + q];
    whh4[idx] = whh[l*12288 + j*64 + 4*c4 + q];
  }
}

// ---------- set2set LSTM weight transpose to [k][j] (coalesced over gate row j) ----------
__global__ void k_s2strans(const float* __restrict__ wih0, const float* __restrict__ whh0,
                           const float* __restrict__ wih1, const float* __restrict__ whh1,
                           float* __restrict__ T){
  int idx = blockIdx.x*256 + threadIdx.x;
  if (idx < 32768){ int k = idx >> 8, j = idx & 255; T[idx] = wih0[j*128 + k]; }
  else if (idx < 49152){ int r = idx - 32768; int k = r >> 8, j = r & 255; T[idx] = whh0[j*64 + k]; }
  else if (idx < 65536){ int r = idx - 49152; int k = r >> 8, j = r & 255; T[idx] = wih1[j*64 + k]; }
  else if (idx < 81920){ int r = idx - 65536; int k = r >> 8, j = r & 255; T[idx] = whh1[j*64 + k]; }
}

// ---------- CSR build ----------
__global__ void k_hist(const int* __restrict__ dst, int* __restrict__ cnt, int E){
  int e = blockIdx.x*blockDim.x + threadIdx.x;
  if (e >= E) return;
  atomicAdd(&cnt[dst[e]], 1);
}
__global__ void k_chunksum(const int* __restrict__ cnt, int* __restrict__ csum, int M){
  __shared__ int sh[256];
  int base = blockIdx.x*1024;
  int s = 0;
  for (int i = threadIdx.x; i < 1024; i += 256){
    int idx = base + i;
    if (idx < M) s += cnt[idx];
  }
  sh[threadIdx.x] = s;
  __syncthreads();
  for (int o = 128; o; o >>= 1){
    if (threadIdx.x < o) sh[threadIdx.x] += sh[threadIdx.x + o];
    __syncthreads();
  }
  if (threadIdx.x == 0) csum[blockIdx.x] = sh[0];
}
__global__ void k_chunkscan(int* __restrict__ csum, int nchunk){
  __shared__ int sh[256];
  int i = threadIdx.x;
  int v = (i < nchunk) ? csum[i] : 0;
  sh[i] = v; __syncthreads();
  for (int o = 1; o < 256; o <<= 1){
    int y = (i >= o) ? sh[i-o] : 0;
    __syncthreads();
    sh[i] += y;
    __syncthreads();
  }
  if (i < nchunk) csum[i] = sh[i] - v;
  if (i == 255) csum[nchunk] = sh[255];
}
__global__ void k_chunkapply(const int* __restrict__ cnt, const int* __restrict__ csum,
                             int* __restrict__ R, int* __restrict__ cur, int M){
  __shared__ int sh[256];
  int base = blockIdx.x*1024;
  int i0 = base + threadIdx.x*4;
  int v[4]; int s = 0;
  #pragma unroll
  for (int k = 0; k < 4; ++k){ int idx = i0 + k; v[k] = (idx < M) ? cnt[idx] : 0; s += v[k]; }
  sh[threadIdx.x] = s; __syncthreads();
  for (int o = 1; o < 256; o <<= 1){
    int y = (threadIdx.x >= o) ? sh[threadIdx.x-o] : 0;
    __syncthreads();
    sh[threadIdx.x] += y;
    __syncthreads();
  }
  int run = csum[blockIdx.x] + sh[threadIdx.x] - s;
  #pragma unroll
  for (int k = 0; k < 4; ++k){
    int idx = i0 + k;
    if (idx < M){ R[idx] = run; cur[idx] = run; run += v[k]; }
  }
  if (threadIdx.x == 255 && base + 1024 >= M) R[M] = csum[blockIdx.x] + sh[255];
}
__global__ void k_scatter(const int* __restrict__ src, const int* __restrict__ dst,
                          const int* __restrict__ etype, int* __restrict__ cur,
                          int* __restrict__ ep, int E){
  int e = blockIdx.x*blockDim.x + threadIdx.x;
  if (e >= E) return;
  int t = etype ? etype[e] : 0;
  int pos = atomicAdd(&cur[dst[e]], 1);
  ep[pos] = (t << 20) | src[e];
}

// ---------- dense transforms: LDS weights + 1 coalesced load + readlane ----------
// tr[t][n][d] = coeff[n] * sum_c h[n][c]*W[t][c][d].
// Per 4-node group: ONE dwordx4/wave; readlane broadcasts; NAMED-SCALAR
// accumulators (arrays spill: r1/r3). Weights in LDS, conflict-free b128.

// 4 matrices in one pass (replaces the r6 tr2 pair): 64 KB LDS, 1024 thr,
// 16 accs + 16 w + 12 misc ~= 55 VGPR; bounds(1024,4) caps 128 -> no spill.
// rl:fma = 1:4 (256 rl : 1024 fma per group). Halves h re-reads vs tr2 pair.
__global__ __launch_bounds__(1024, 4) void k_tr4d(
    const float* __restrict__ h, const float* __restrict__ W4,
    const float* __restrict__ coeff, float* __restrict__ tr, int N){
  extern __shared__ float4 wl[];           // [4][1024] = 64 KB
  for (int i = threadIdx.x; i < 4096; i += 1024) wl[i] = ((const float4*)W4)[i];
  __syncthreads();
  int lane = threadIdx.x & 63, wv = threadIdx.x >> 6;   // 16 waves
  int ng = N >> 2, stride = gridDim.x*16;
  for (int g = blockIdx.x*16 + wv; g < ng; g += stride){
    int n0 = g << 2;
    float4 ld = ((const float4*)(h + ((size_t)n0 << 6)))[lane];
    float a00=0.f,a01=0.f,a02=0.f,a03=0.f;
    float a10=0.f,a11=0.f,a12=0.f,a13=0.f;
    float a20=0.f,a21=0.f,a22=0.f,a23=0.f;
    float a30=0.f,a31=0.f,a32=0.f,a33=0.f;
    for (int c4 = 0; c4 < 16; ++c4){
      int wb = (c4 << 6) + lane;
      float4 w0 = wl[wb], w1 = wl[1024+wb], w2 = wl[2048+wb], w3 = wl[3072+wb];
      float hx, hy, hz, hw;
      RL4(c4)     FMA4(a00,w0) FMA4(a10,w1) FMA4(a20,w2) FMA4(a30,w3)
      RL4(16|c4)  FMA4(a01,w0) FMA4(a11,w1) FMA4(a21,w2) FMA4(a31,w3)
      RL4(32|c4)  FMA4(a02,w0) FMA4(a12,w1) FMA4(a22,w2) FMA4(a32,w3)
      RL4(48|c4)  FMA4(a03,w0) FMA4(a13,w1) FMA4(a23,w2) FMA4(a33,w3)
    }
    float4 cv = ((const float4*)coeff)[g];
    a00*=cv.x; a01*=cv.y; a02*=cv.z; a03*=cv.w;
    a10*=cv.x; a11*=cv.y; a12*=cv.z; a13*=cv.w;
    a20*=cv.x; a21*=cv.y; a22*=cv.z; a23*=cv.w;
    a30*=cv.x; a31*=cv.y; a32*=cv.z; a33*=cv.w;
    float* o0 = tr + ((size_t)n0 << 6) + lane;
    o0[0]=a00; o0[64]=a01; o0[128]=a02; o0[192]=a03;
    float* o1 = tr + (((size_t)N + n0) << 6) + lane;
    o1[0]=a10; o1[64]=a11; o1[128]=a12; o1[192]=a13;
    float* o2 = tr + (((size_t)2*N + n0) << 6) + lane;
    o2[0]=a20; o2[64]=a21; o2[128]=a22; o2[192]=a23;
    float* o3 = tr + (((size_t)3*N + n0) << 6) + lane;
    o3[0]=a30; o3[64]=a31; o3[128]=a32; o3[192]=a33;
  }
}

// single-matrix variant (level-2; also tr4d fallback), 16 KB static LDS
__global__ __launch_bounds__(256) void k_tr1(
    const float* __restrict__ h, const float* __restrict__ W4,
    const float* __restrict__ coeff, float* __restrict__ tr, int N){
  __shared__ float4 wl[1024];                 // 16 KB
  for (int i = threadIdx.x; i < 1024; i += 256) wl[i] = ((const float4*)W4)[i];
  __syncthreads();
  int lane = threadIdx.x & 63, w = threadIdx.x >> 6;
  int ng = N >> 2, stride = gridDim.x*4;
  for (int g = blockIdx.x*4 + w; g < ng; g += stride){
    int n0 = g << 2;
    float4 ld = ((const float4*)(h + ((size_t)n0 << 6)))[lane];
    float a0=0.f, a1=0.f, a2=0.f, a3=0.f;
    for (int c4 = 0; c4 < 16; ++c4){
      float4 w0 = wl[(c4 << 6) + lane];
      float hx, hy, hz, hw;
      RL4(c4)       FMA4(a0, w0)
      RL4(16|c4)    FMA4(a1, w0)
      RL4(32|c4)    FMA4(a2, w0)
      RL4(48|c4)    FMA4(a3, w0)
    }
    if (coeff){
      float4 cv = ((const float4*)coeff)[g];
      a0 *= cv.x; a1 *= cv.y; a2 *= cv.z; a3 *= cv.w;
    }
    float* o0 = tr + ((size_t)n0 << 6) + lane;
    o0[0] = a0; o0[64] = a1; o0[128] = a2; o0[192] = a3;
  }
}

// ---------- merged sweep (gather tr rows per dst via CSR) ----------
__global__ void k_sweep_p(const float* __restrict__ tr, const int* __restrict__ R,
                          const int* __restrict__ ep, float* __restrict__ aggr, int N){
  int w = threadIdx.x >> 6, lane = threadIdx.x & 63;
  int d = blockIdx.x*4 + w;
  if (d >= N) return;
  int p = R[d], pend = R[d+1];
  float acc = 0.f;
  while (p < pend){
    int m = pend - p; if (m > 64) m = 64;
    int ev = (lane < m) ? ep[p + lane] : 0;
    for (int j = 0; j < m; ++j){
      int pk = __shfl(ev, j);
      int s = pk & 0xFFFFF, t = pk >> 20;
      acc += tr[((size_t)t*N + s)*64 + lane];
    }
    p += m;
  }
  aggr[(size_t)d*64 + lane] = acc;
}

// ---------- tr3: GRU-fallback gi transform (LDS weights + readlane) ----------
__global__ __launch_bounds__(256) void k_tr3(
    const float* __restrict__ h, const float* __restrict__ W4,
    float* __restrict__ tr, int N){
  __shared__ float4 wl[3072];                 // 48 KB (3 matrices)
  for (int i = threadIdx.x; i < 3072; i += 256) wl[i] = ((const float4*)W4)[i];
  __syncthreads();
  int lane = threadIdx.x & 63, w = threadIdx.x >> 6;
  int ng = N >> 2, stride = gridDim.x*4;
  for (int g = blockIdx.x*4 + w; g < ng; g += stride){
    int n0 = g << 2;
    float4 ld = ((const float4*)(h + ((size_t)n0 << 6)))[lane];
    float a00=0.f,a01=0.f,a02=0.f,a03=0.f;
    float a10=0.f,a11=0.f,a12=0.f,a13=0.f;
    float a20=0.f,a21=0.f,a22=0.f,a23=0.f;
    for (int c4 = 0; c4 < 16; ++c4){
      float4 w0 = wl[(c4 << 6) + lane];
      float4 w1 = wl[1024 + (c4 << 6) + lane];
      float4 w2 = wl[2048 + (c4 << 6) + lane];
      float hx, hy, hz, hw;
      RL4(c4)       FMA4(a00, w0) FMA4(a10, w1) FMA4(a20, w2)
      RL4(16|c4)    FMA4(a01, w0) FMA4(a11, w1) FMA4(a21, w2)
      RL4(32|c4)    FMA4(a02, w0) FMA4(a12, w1) FMA4(a22, w2)
      RL4(48|c4)    FMA4(a03, w0) FMA4(a13, w1) FMA4(a23, w2)
    }
    float* o0 = tr + ((size_t)n0 << 6) + lane;
    o0[0] = a00; o0[64] = a01; o0[128] = a02; o0[192] = a03;
    float* o1 = tr + (((size_t)N + n0) << 6) + lane;
    o1[0] = a10; o1[64] = a11; o1[128] = a12; o1[192] = a13;
    float* o2 = tr + (((size_t)2*N + n0) << 6) + lane;
    o2[0] = a20; o2[64] = a21; o2[128] = a22; o2[192] = a23;
  }
}

// ---------- fully fused GRU: both GEMVs + pointwise in ONE kernel ----------
// wih AND whh in LDS (96KB, 1 block/CU, 16 waves = 4/SIMD). GRU algebra folds
// gi_r+gh_r and gi_z+gh_z into single accumulators. Per 4-node group: 2
// coalesced dwordx4 loads, 96 conflict-free ds_read_b128, 512 rl + 1536 fma,
// in-lane pointwise, ZERO barriers in the loop.  [round 6: -950us]
#define RLAH(SL) \
  ax = rlane(la.x, SL); ay = rlane(la.y, SL); az2 = rlane(la.z, SL); aw = rlane(la.w, SL); \
  hx = rlane(ld.x, SL); hy = rlane(ld.y, SL); hz  = rlane(ld.z, SL); hw = rlane(ld.w, SL);
#define GACC(SL, R, Z, P, Q) RLAH(SL) \
  R = fmaf(ax,iwr.x,R); R = fmaf(ay,iwr.y,R); R = fmaf(az2,iwr.z,R); R = fmaf(aw,iwr.w,R); \
  R = fmaf(hx,hwr.x,R); R = fmaf(hy,hwr.y,R); R = fmaf(hz,hwr.z,R);  R = fmaf(hw,hwr.w,R); \
  Z = fmaf(ax,iwz.x,Z); Z = fmaf(ay,iwz.y,Z); Z = fmaf(az2,iwz.z,Z); Z = fmaf(aw,iwz.w,Z); \
  Z = fmaf(hx,hwz.x,Z); Z = fmaf(hy,hwz.y,Z); Z = fmaf(hz,hwz.z,Z);  Z = fmaf(hw,hwz.w,Z); \
  P = fmaf(ax,iwn.x,P); P = fmaf(ay,iwn.y,P); P = fmaf(az2,iwn.z,P); P = fmaf(aw,iwn.w,P); \
  Q = fmaf(hx,hwn.x,Q); Q = fmaf(hy,hwn.y,Q); Q = fmaf(hz,hwn.z,Q);  Q = fmaf(hw,hwn.w,Q);
#define GFIN(K, R, Z, P, Q) { \
    size_t off = base + ((size_t)(K) << 6) + lane; \
    float hv = h[off]; \
    float r = sigf(R), z = sigf(Z); \
    float nn = tanhf(P + r*Q); \
    h[off] = (1.f - z)*nn + z*hv; }
__global__ __launch_bounds__(1024, 4) void k_gru_fused(
    const float* __restrict__ aggr, float* __restrict__ h,
    const float* __restrict__ wihW, const float* __restrict__ whhW,
    const float* __restrict__ bih, const float* __restrict__ bhh, int N){
  extern __shared__ float4 wl[];           // [6144]: wih | whh, 96 KB
  for (int i = threadIdx.x; i < 6144; i += 1024)
    wl[i] = (i < 3072) ? ((const float4*)wihW)[i] : ((const float4*)whhW)[i - 3072];
  __syncthreads();
  const float4* wi = wl;
  const float4* wh = wl + 3072;
  int lane = threadIdx.x & 63, wv = threadIdx.x >> 6;
  float br  = bih[lane]     + bhh[lane];
  float bz  = bih[64+lane]  + bhh[64+lane];
  float bp  = bih[128+lane];                // gi_n bias
  float bq  = bhh[128+lane];                // gh_n bias
  int ng = N >> 2, stride = gridDim.x*16;
  for (int g = blockIdx.x*16 + wv; g < ng; g += stride){
    int n0 = g << 2;
    size_t base = (size_t)n0 << 6;
    float4 la = ((const float4*)(aggr + base))[lane];
    float4 ld = ((const float4*)(h + base))[lane];
    float r0=br, r1=br, r2=br, r3=br;
    float z0=bz, z1=bz, z2=bz, z3=bz;
    float p0=bp, p1=bp, p2=bp, p3=bp;
    float q0=bq, q1=bq, q2=bq, q3=bq;
    for (int c4 = 0; c4 < 16; ++c4){
      int wb = c4*192 + lane;
      float4 iwr = wi[wb], iwz = wi[wb+64], iwn = wi[wb+128];
      float4 hwr = wh[wb], hwz = wh[wb+64], hwn = wh[wb+128];
      float ax, ay, az2, aw, hx, hy, hz, hw;
      GACC(c4,    r0, z0, p0, q0)
      GACC(16|c4, r1, z1, p1, q1)
      GACC(32|c4, r2, z2, p2, q2)
      GACC(48|c4, r3, z3, p3, q3)
    }
    GFIN(0, r0, z0, p0, q0)
    GFIN(1, r1, z1, p1, q1)
    GFIN(2, r2, z2, p2, q2)
    GFIN(3, r3, z3, p3, q3)
  }
}

// ---------- GRU finalize fallback (used only if 96KB dynamic LDS refused) ----------
#define GRUACC(SL, RK, ZK, NK) RL4(SL) FMA4(RK, wr) FMA4(ZK, wz) FMA4(NK, wn)
#define GRUFIN(K, RK, ZK, NK) { \
    size_t off = base + (K << 6) + lane; \
    float gir = gi[off], giz = gi[S + off], gin = gi[2*S + off]; \
    float hv = h[off]; \
    float r = sigf(gir + bir + RK); \
    float z = sigf(giz + biz + ZK); \
    float nv = tanhf(gin + bin_ + r*NK); \
    h[off] = (1.f - z)*nv + z*hv; }
__global__ __launch_bounds__(256, 3) void k_gru_finW(
    const float* __restrict__ gi, float* __restrict__ h,
    const float* __restrict__ whh4,
    const float* __restrict__ bih, const float* __restrict__ bhh, int N){
  __shared__ float4 wh[3072];              // [c4][192] = whh[j][4c4+q], 48KB
  for (int i = threadIdx.x; i < 3072; i += 256) wh[i] = ((const float4*)whh4)[i];
  __syncthreads();
  int lane = threadIdx.x & 63, w = threadIdx.x >> 6;
  float bir = bih[lane], biz = bih[64+lane], bin_ = bih[128+lane];
  float bhr = bhh[lane], bhz = bhh[64+lane], bhn = bhh[128+lane];
  size_t S = (size_t)N << 6;
  int ng = N >> 2, stride = gridDim.x*4;
  for (int g = blockIdx.x*4 + w; g < ng; g += stride){
    int n0 = g << 2;
    size_t base = (size_t)n0 << 6;
    float4 ld = ((const float4*)(h + base))[lane];
    float ar0=bhr, ar1=bhr, ar2=bhr, ar3=bhr;
    float az0=bhz, az1=bhz, az2=bhz, az3=bhz;
    float an0=bhn, an1=bhn, an2=bhn, an3=bhn;
    for (int c4 = 0; c4 < 16; ++c4){
      int wb = c4*192 + lane;
      float4 wr = wh[wb];
      float4 wz = wh[wb + 64];
      float4 wn = wh[wb + 128];
      float hx, hy, hz, hw;
      GRUACC(c4,    ar0, az0, an0)
      GRUACC(16|c4, ar1, az1, an1)
      GRUACC(32|c4, ar2, az2, an2)
      GRUACC(48|c4, ar3, az3, an3)
    }
    GRUFIN(0, ar0, az0, an0)
    GRUFIN(1, ar1, az1, an1)
    GRUFIN(2, ar2, az2, an2)
    GRUFIN(3, ar3, az3, an3)
  }
}

// ---------- batch norm over nodes ----------
__global__ void k_bnstats(const float* __restrict__ h, float* __restrict__ stats, int N){
  int c = threadIdx.x & 63;
  int g = threadIdx.x >> 6;
  float s = 0.f, s2 = 0.f;
  for (int n = blockIdx.x*4 + g; n < N; n += gridDim.x*4){
    float v = h[(size_t)n*64 + c]; s += v; s2 += v*v;
  }
  __shared__ float sh[4][64], sh2[4][64];
  sh[g][c] = s; sh2[g][c] = s2;
  __syncthreads();
  if (g == 0){
    float ts = sh[0][c]+sh[1][c]+sh[2][c]+sh[3][c];
    float t2 = sh2[0][c]+sh2[1][c]+sh2[2][c]+sh2[3][c];
    atomicAdd(&stats[c], ts); atomicAdd(&stats[64+c], t2);
  }
}
__global__ void k_bnapply(float* __restrict__ h, const float* __restrict__ stats,
                          const float* __restrict__ g, const float* __restrict__ b,
                          int N, int relu){
  int i = blockIdx.x*blockDim.x + threadIdx.x;
  if (i >= N*64) return;
  int c = i & 63;
  float inv = 1.f/(float)N;
  float mean = stats[c]*inv;
  float var  = stats[64+c]*inv - mean*mean;
  float y = (h[i]-mean)*rsqrtf(var + 1e-5f)*g[c] + b[c];
  if (relu) y = fmaxf(y, 0.f);
  h[i] = y;
}

// ---------- avg_pool ----------
__global__ void k_pool_acc(const float* __restrict__ h, const int* __restrict__ asrc,
                           const int* __restrict__ adst, float* __restrict__ h2,
                           float* __restrict__ cnt, int A){
  int i = blockIdx.x*blockDim.x + threadIdx.x;
  if (i >= A*64) return;
  int a = i >> 6, c = i & 63;
  int s = asrc[a], d = adst[a];
  atomicAdd(&h2[(size_t)d*64 + c], h[(size_t)s*64 + c]);
  if (c == 0) atomicAdd(&cnt[d], 1.f);
}
__global__ void k_pool_div(float* __restrict__ h2, const float* __restrict__ cnt, int N){
  int i = blockIdx.x*blockDim.x + threadIdx.x;
  if (i >= N*64) return;
  h2[i] = h2[i] / fmaxf(cnt[i >> 6], 1.f);
}

// ---------- fully fused set2set: one block (1024 thr = 16 waves) per graph ----------
__global__ __launch_bounds__(1024) void k_set2set(const float* __restrict__ x, const int* __restrict__ rb,
                          const float* __restrict__ T,
                          const float* __restrict__ b0, const float* __restrict__ b1,
                          float* __restrict__ xout){
  int b = blockIdx.x, j = threadIdx.x;
  int w = j >> 6, lane = j & 63;
  __shared__ float qstar[128], h0[64], c0[64], h1[64], c1[64];
  __shared__ float gs[256], wmax[16], wsum[16], racc[16][64];
  if (j < 128) qstar[j] = 0.f;
  if (j < 64){ h0[j] = 0.f; c0[j] = 0.f; h1[j] = 0.f; c1[j] = 0.f; }
  __syncthreads();
  int n0 = rb[b], n1 = rb[b+1];
  const float* T0 = T;            // wih0T [128][256]
  const float* T1 = T + 32768;    // whh0T [64][256]
  const float* T2 = T + 49152;    // wih1T [64][256]
  const float* T3 = T + 65536;    // whh1T [64][256]
  for (int s = 0; s < 5; ++s){
    if (j < 256){
      float a0 = b0[j], a1 = 0.f, a2 = 0.f, a3 = 0.f;
      #pragma unroll 4
      for (int k = 0; k < 128; k += 4){
        a0 = fmaf(T0[(k+0)*256 + j], qstar[k+0], a0);
        a1 = fmaf(T0[(k+1)*256 + j], qstar[k+1], a1);
        a2 = fmaf(T0[(k+2)*256 + j], qstar[k+2], a2);
        a3 = fmaf(T0[(k+3)*256 + j], qstar[k+3], a3);
      }
      #pragma unroll 4
      for (int k = 0; k < 64; k += 4){
        a0 = fmaf(T1[(k+0)*256 + j], h0[k+0], a0);
        a1 = fmaf(T1[(k+1)*256 + j], h0[k+1], a1);
        a2 = fmaf(T1[(k+2)*256 + j], h0[k+2], a2);
        a3 = fmaf(T1[(k+3)*256 + j], h0[k+3], a3);
      }
      gs[j] = (a0 + a1) + (a2 + a3);
    }
    __syncthreads();
    if (j < 64){
      float ig = sigf(gs[j]);
      float fg = sigf(gs[64+j]);
      float gg = tanhf(gs[128+j]);
      float og = sigf(gs[192+j]);
      float cn = fg*c0[j] + ig*gg;
      c0[j] = cn;
      h0[j] = og*tanhf(cn);
    }
    __syncthreads();
    if (j < 256){
      float a0 = b1[j], a1 = 0.f, a2 = 0.f, a3 = 0.f;
      #pragma unroll 4
      for (int k = 0; k < 64; k += 4){
        a0 = fmaf(T2[(k+0)*256 + j], h0[k+0], a0);
        a1 = fmaf(T2[(k+1)*256 + j], h0[k+1], a1);
        a2 = fmaf(T2[(k+2)*256 + j], h0[k+2], a2);
        a3 = fmaf(T2[(k+3)*256 + j], h0[k+3], a3);
      }
      #pragma unroll 4
      for (int k = 0; k < 64; k += 4){
        a0 = fmaf(T3[(k+0)*256 + j], h1[k+0], a0);
        a1 = fmaf(T3[(k+1)*256 + j], h1[k+1], a1);
        a2 = fmaf(T3[(k+2)*256 + j], h1[k+2], a2);
        a3 = fmaf(T3[(k+3)*256 + j], h1[k+3], a3);
      }
      gs[j] = (a0 + a1) + (a2 + a3);
    }
    __syncthreads();
    if (j < 64){
      float ig = sigf(gs[j]);
      float fg = sigf(gs[64+j]);
      float gg = tanhf(gs[128+j]);
      float og = sigf(gs[192+j]);
      float cn = fg*c1[j] + ig*gg;
      c1[j] = cn;
      float hn = og*tanhf(cn);
      h1[j] = hn;
      qstar[j] = hn;
    }
    __syncthreads();
    float lmax = -3.4e38f;
    for (int n = n0 + w; n < n1; n += 16){
      float v = x[(size_t)n*64 + lane]*qstar[lane];
      #pragma unroll
      for (int o = 32; o; o >>= 1) v += __shfl_xor(v, o);
      lmax = fmaxf(lmax, v);
    }
    if (lane == 0) wmax[w] = lmax;
    __syncthreads();
    float bmax = wmax[0];
    #pragma unroll
    for (int k = 1; k < 16; ++k) bmax = fmaxf(bmax, wmax[k]);
    float lsum = 0.f, lr = 0.f;
    for (int n = n0 + w; n < n1; n += 16){
      float xv = x[(size_t)n*64 + lane];
      float v = xv*qstar[lane];
      #pragma unroll
      for (int o = 32; o; o >>= 1) v += __shfl_xor(v, o);
      float wexp = expf(v - bmax);
      lsum += wexp;
      lr = fmaf(wexp, xv, lr);
    }
    if (lane == 0) wsum[w] = lsum;
    racc[w][lane] = lr;
    __syncthreads();
    if (j < 64){
      float r = 0.f, denom = 0.f;
      #pragma unroll
      for (int k = 0; k < 16; ++k){ r += racc[k][j]; denom += wsum[k]; }
      qstar[64 + j] = (denom > 0.f) ? (r/denom) : 0.f;
    }
    __syncthreads();
  }
  if (j < 128) xout[(size_t)b*128 + j] = qstar[j];
}

// ---------- head ----------
__global__ void k_concat(const float* __restrict__ x1, const float* __restrict__ x2,
                         float* __restrict__ z){
  int i = blockIdx.x*blockDim.x + threadIdx.x;
  if (i >= 256*256) return;
  int b = i >> 8, c = i & 255;
  z[i] = (c < 128) ? x1[b*128 + c] : x2[b*128 + (c - 128)];
}
__global__ void k_bn_par(float* __restrict__ X, const float* __restrict__ g,
                         const float* __restrict__ b, int F, int relu){
  int f = blockIdx.x, i = threadIdx.x;
  float v = X[(size_t)i*F + f];
  __shared__ float s1[256], s2[256];
  s1[i] = v; s2[i] = v*v;
  __syncthreads();
  for (int o = 128; o; o >>= 1){
    if (i < o){ s1[i] += s1[i+o]; s2[i] += s2[i+o]; }
    __syncthreads();
  }
  float mean = s1[0]*(1.f/256.f);
  float var  = s2[0]*(1.f/256.f) - mean*mean;
  float y = (v - mean)*rsqrtf(var + 1e-5f)*g[f] + b[f];
  if (relu) y = fmaxf(y, 0.f);
  X[(size_t)i*F + f] = y;
}
__global__ void k_fc(const float* __restrict__ X, const float* __restrict__ W,
                     const float* __restrict__ bias, float* __restrict__ Y, int K, int F){
  int b = blockIdx.x, f = threadIdx.x;
  if (f >= F) return;
  const float* xr = X + (size_t)b*K;
  const float* wr = W + (size_t)f*K;
  float acc = bias[f];
  for (int k = 0; k < K; ++k) acc = fmaf(xr[k], wr[k], acc);
  Y[(size_t)b*F + f] = acc;
}
__global__ void k_fc_out(const float* __restrict__ z2, const float* __restrict__ w,
                         const float* __restrict__ bias, float* __restrict__ out){
  int b = blockIdx.x*blockDim.x + threadIdx.x;
  if (b >= 256) return;
  float acc = bias[0];
  #pragma unroll
  for (int k = 0; k < 64; ++k) acc = fmaf(z2[b*64 + k], w[k], acc);
  out[b] = acc;
}

extern "C" void kernel_launch(void* const* d_in, const int* in_sizes, int n_in,
                              void* d_out, int out_size, void* d_ws, size_t ws_size,
                              hipStream_t stream) {
  const float* x_in     = (const float*)d_in[0];
  const float* edge_attr= (const float*)d_in[1];
  const float* conv_w   = (const float*)d_in[2];
  const float* conv_wih = (const float*)d_in[3];
  const float* conv_whh = (const float*)d_in[4];
  const float* conv_bih = (const float*)d_in[5];
  const float* conv_bhh = (const float*)d_in[6];
  const float* conv_nt  = (const float*)d_in[7];
  const float* s1_wih0 = (const float*)d_in[8];
  const float* s1_whh0 = (const float*)d_in[9];
  const float* s1_b0   = (const float*)d_in[10];
  const float* s1_wih1 = (const float*)d_in[11];
  const float* s1_whh1 = (const float*)d_in[12];
  const float* s1_b1   = (const float*)d_in[13];
  const float* s2_wih0 = (const float*)d_in[14];
  const float* s2_whh0 = (const float*)d_in[15];
  const float* s2_b0   = (const float*)d_in[16];
  const float* s2_wih1 = (const float*)d_in[17];
  const float* s2_whh1 = (const float*)d_in[18];
  const float* s2_b1   = (const float*)d_in[19];
  const float* bn_g    = (const float*)d_in[20];
  const float* bn_b    = (const float*)d_in[21];
  const float* prebn_g = (const float*)d_in[22];
  const float* prebn_b = (const float*)d_in[23];
  const float* fc_w0   = (const float*)d_in[24];
  const float* fc_b0   = (const float*)d_in[25];
  const float* fc_w1   = (const float*)d_in[26];
  const float* fc_b1   = (const float*)d_in[27];
  const float* fc_w2   = (const float*)d_in[28];
  const float* fc_b2   = (const float*)d_in[29];
  const float* fcbn_g0 = (const float*)d_in[30];
  const float* fcbn_b0 = (const float*)d_in[31];
  const float* fcbn_g1 = (const float*)d_in[32];
  const float* fcbn_b1 = (const float*)d_in[33];
  const int* edge_index   = (const int*)d_in[34];
  const int* node_type    = (const int*)d_in[35];
  const int* batch        = (const int*)d_in[36];
  const int* assign_src   = (const int*)d_in[37];
  const int* assign_dst   = (const int*)d_in[38];
  const int* edge_index_2 = (const int*)d_in[39];
  const int* batch_2      = (const int*)d_in[40];
  (void)in_sizes; (void)n_in; (void)out_size; (void)ws_size;

  // dynamic-LDS opt-ins (host-side, graph-capture-safe). 96KB proven in r6.
  int fused_ok = (hipFuncSetAttribute((const void*)k_gru_fused,
                    hipFuncAttributeMaxDynamicSharedMemorySize, 98304) == hipSuccess);
  int tr4_ok = (hipFuncSetAttribute((const void*)k_tr4d,
                    hipFuncAttributeMaxDynamicSharedMemorySize, 65536) == hipSuccess);

  // ---- workspace layout ----
  float* Wp = (float*)d_ws;
  size_t o = 0;
  auto alloc = [&](size_t n){ float* p = Wp + o; o += n; return p; };
  float* h     = alloc((size_t)NN1*64);
  float* tr    = alloc((size_t)4*NN1*64);   // tr slabs; gi slabs in GRU fallback
  float* aggr  = alloc((size_t)NN1*64);
  float* coeff = alloc(NN1);
  float* h2    = alloc((size_t)NN2*64);
  float* cnt   = alloc(NN2);
  float* x1    = alloc(256*128);
  float* x2    = alloc(256*128);
  float* z     = alloc(256*256);
  float* z1    = alloc(256*128);
  float* z2    = alloc(256*64);
  float* stats = alloc(128);
  float* w4    = alloc(245760);
  float* wihT  = alloc(61440);
  float* wihW  = alloc(61440);
  float* whh4  = alloc(61440);
  float* s2sT1 = alloc(81920);
  float* s2sT2 = alloc(81920);
  int* etype = (int*)alloc(EE1);
  int* cnt1  = (int*)alloc(NN1);
  int* R1    = (int*)alloc(NN1 + 1);
  int* ep1   = (int*)alloc(EE1);
  int* cnt2  = (int*)alloc(NN2);
  int* R2    = (int*)alloc(NN2 + 1);
  int* ep2   = (int*)alloc(EE2);
  int* csum  = (int*)alloc(260);
  int* rb1   = (int*)alloc(257);
  int* rb2   = (int*)alloc(257);

  const int* src1 = edge_index;
  const int* dst1 = edge_index + EE1;
  const int* src2 = edge_index_2;
  const int* dst2 = edge_index_2 + EE2;

  k_etype<<<(EE1+255)/256, 256, 0, stream>>>(edge_attr, etype, EE1);
  k_copy<<<(NN1*64+255)/256, 256, 0, stream>>>(x_in, h, NN1*64);
  k_prep_msgw<<<(245760+255)/256, 256, 0, stream>>>(conv_w, w4);
  k_prep_gruw<<<(61440+255)/256, 256, 0, stream>>>(conv_wih, conv_whh, wihT, wihW, whh4);
  k_s2strans<<<(81920+255)/256, 256, 0, stream>>>(s1_wih0, s1_whh0, s1_wih1, s1_whh1, s2sT1);
  k_s2strans<<<(81920+255)/256, 256, 0, stream>>>(s2_wih0, s2_whh0, s2_wih1, s2_whh1, s2sT2);
  k_batchptr<<<(NN1+255)/256, 256, 0, stream>>>(batch, rb1, NN1, 256);
  k_batchptr<<<(NN2+255)/256, 256, 0, stream>>>(batch_2, rb2, NN2, 256);

  {  // level-1 CSR (keys = dst; etype packed into edge payload)
    int M = NN1, nchunk = (M + 1023)/1024;
    hipMemsetAsync(cnt1, 0, (size_t)M*sizeof(int), stream);
    k_hist<<<(EE1+255)/256, 256, 0, stream>>>(dst1, cnt1, EE1);
    k_chunksum<<<nchunk, 256, 0, stream>>>(cnt1, csum, M);
    k_chunkscan<<<1, 256, 0, stream>>>(csum, nchunk);
    k_chunkapply<<<nchunk, 256, 0, stream>>>(cnt1, csum, R1, cnt1, M);
    k_scatter<<<(EE1+255)/256, 256, 0, stream>>>(src1, dst1, etype, cnt1, ep1, EE1);
  }
  {  // level-2 CSR
    int M = NN2, nchunk = (M + 1023)/1024;
    hipMemsetAsync(cnt2, 0, (size_t)M*sizeof(int), stream);
    k_hist<<<(EE2+255)/256, 256, 0, stream>>>(dst2, cnt2, EE2);
    k_chunksum<<<nchunk, 256, 0, stream>>>(cnt2, csum, M);
    k_chunkscan<<<1, 256, 0, stream>>>(csum, nchunk);
    k_chunkapply<<<nchunk, 256, 0, stream>>>(cnt2, csum, R2, cnt2, M);
    k_scatter<<<(EE2+255)/256, 256, 0, stream>>>(src2, dst2, nullptr, cnt2, ep2, EE2);
  }

  // GRU: fused (gi+gh+pointwise, 96KB LDS) or fallback (tr3 + finW)
  auto gru = [&](float* hbuf, int N, int lidx){
    if (fused_ok){
      k_gru_fused<<<256, 1024, 98304, stream>>>(aggr, hbuf,
          wihW + (size_t)lidx*12288, whh4 + (size_t)lidx*12288,
          conv_bih + lidx*192, conv_bhh + lidx*192, N);
    } else {
      k_tr3<<<768, 256, 0, stream>>>(aggr, wihT + (size_t)lidx*12288, tr, N);
      k_gru_finW<<<768, 256, 0, stream>>>(tr, hbuf, whh4 + (size_t)lidx*12288,
          conv_bih + lidx*192, conv_bhh + lidx*192, N);
    }
  };

  // ---- level-1: 3x MGGC(L=3) + BN + ReLU ----
  for (int i = 0; i < 3; ++i){
    k_coeff<<<(NN1+255)/256, 256, 0, stream>>>(conv_nt + i*9, node_type, coeff, NN1);
    for (int l = 0; l < 3; ++l){
      const float* W4l = w4 + (size_t)(i*3+l)*16384;   // 4 matrices, float4 layout
      if (tr4_ok){
        k_tr4d<<<512, 1024, 65536, stream>>>(h, W4l, coeff, tr, NN1);
      } else {
        for (int t = 0; t < 4; ++t)
          k_tr1<<<1024, 256, 0, stream>>>(h, W4l + (size_t)t*4096, coeff,
                                          tr + (size_t)t*NN1*64, NN1);
      }
      k_sweep_p<<<(NN1+3)/4, 256, 0, stream>>>(tr, R1, ep1, aggr, NN1);
      gru(h, NN1, i);
    }
    hipMemsetAsync(stats, 0, 128*sizeof(float), stream);
    k_bnstats<<<256, 256, 0, stream>>>(h, stats, NN1);
    k_bnapply<<<(NN1*64+255)/256, 256, 0, stream>>>(h, stats, bn_g + i*64, bn_b + i*64, NN1, 1);
  }

  // ---- set2set (single fused kernel, 1024 threads/graph) ----
  k_set2set<<<256, 1024, 0, stream>>>(h, rb1, s2sT1, s1_b0, s1_b1, x1);

  // ---- avg_pool ----
  hipMemsetAsync(h2, 0, (size_t)NN2*64*sizeof(float), stream);
  hipMemsetAsync(cnt, 0, (size_t)NN2*sizeof(float), stream);
  k_pool_acc<<<(AA*64+255)/256, 256, 0, stream>>>(h, assign_src, assign_dst, h2, cnt, AA);
  k_pool_div<<<(NN2*64+255)/256, 256, 0, stream>>>(h2, cnt, NN2);

  // ---- level-2: 2x relu(MGGC(L=3)), only edge type 0 ----
  for (int L = 3; L < 5; ++L){
    for (int l = 0; l < 3; ++l){
      const float* W4l = w4 + (size_t)(L*3+l)*16384;   // t=0 slice used
      k_tr1<<<1250, 256, 0, stream>>>(h2, W4l, nullptr, tr, NN2);
      k_sweep_p<<<(NN2+3)/4, 256, 0, stream>>>(tr, R2, ep2, aggr, NN2);
      gru(h2, NN2, L);
    }
    k_relu<<<(NN2*64+255)/256, 256, 0, stream>>>(h2, NN2*64);
  }

  k_set2set<<<256, 1024, 0, stream>>>(h2, rb2, s2sT2, s2_b0, s2_b1, x2);

  // ---- head ----
  k_concat<<<256, 256, 0, stream>>>(x1, x2, z);
  k_bn_par<<<256, 256, 0, stream>>>(z, prebn_g, prebn_b, 256, 0);
  k_fc<<<256, 128, 0, stream>>>(z, fc_w0, fc_b0, z1, 256, 128);
  k_bn_par<<<128, 256, 0, stream>>>(z1, fcbn_g0, fcbn_b0, 128, 1);
  k_fc<<<256, 64, 0, stream>>>(z1, fc_w1, fc_b1, z2, 128, 64);
  k_bn_par<<<64, 256, 0, stream>>>(z2, fcbn_g1, fcbn_b1, 64, 1);
  k_fc_out<<<4, 64, 0, stream>>>(z2, fc_w2, fc_b2, (float*)d_out);
}